// Round 5
// baseline (621.847 us; speedup 1.0000x reference)
//
#include <hip/hip_runtime.h>
#include <hip/hip_fp16.h>
#include <stdint.h>

#define Q_MAX 127.0f
#define EPSQ 1e-5f

typedef int v4i __attribute__((ext_vector_type(4)));

#define BM 128
#define BN 128
#define BK 64

__device__ __forceinline__ void async16(const void* g, const void* l) {
    __builtin_amdgcn_global_load_lds((const __attribute__((address_space(1))) uint32_t*)g,
                                     (__attribute__((address_space(3))) uint32_t*)l,
                                     16, 0, 0);
}
__device__ __forceinline__ int pack4i(int a, int b, int c, int d) {
    return (a & 0xff) | ((b & 0xff) << 8) | ((c & 0xff) << 16) | (d << 24);
}
// reference epilogue: fp16(acc*sm*scw) + fp16(bias), computed in fp16, returned as f32
__device__ __forceinline__ float ep(float v, float b) {
    return __half2float(__hadd(__float2half(v), __float2half(b)));
}

// ---------------- weight repack: int32 [N,K] -> int8 [N,K] (fast path only) --------
__global__ __launch_bounds__(256) void pack_w(const int* __restrict__ w32,
                                              int8_t* __restrict__ w8) {
    const size_t i = ((size_t)blockIdx.x * 256 + threadIdx.x) * 16;  // 16 elems/thread
    const int4* src = (const int4*)(w32 + i);
    int4 a = src[0], b = src[1], c = src[2], d = src[3];
    int out[4] = { pack4i(a.x,a.y,a.z,a.w), pack4i(b.x,b.y,b.z,b.w),
                   pack4i(c.x,c.y,c.z,c.w), pack4i(d.x,d.y,d.z,d.w) };
    *(int4*)(w8 + i) = *(const int4*)out;
}

// ---------------- activation quantization: one block per row, K=4096 ----------------
__global__ __launch_bounds__(256) void quant_rows(const float* __restrict__ x,   // f32 (fp16 values)
                                                  int8_t* __restrict__ xq,
                                                  float* __restrict__ scales,
                                                  int K) {
    const int row = blockIdx.x;
    const int t   = threadIdx.x;
    const float4* xr4 = (const float4*)(x + (size_t)row * K);
    float4 v[4];
#pragma unroll
    for (int i = 0; i < 4; ++i) v[i] = xr4[t * 4 + i];
    const float* vals = (const float*)v;

    float amax = 0.f;
#pragma unroll
    for (int i = 0; i < 16; ++i) amax = fmaxf(amax, fabsf(vals[i]));
#pragma unroll
    for (int off = 32; off >= 1; off >>= 1)
        amax = fmaxf(amax, __shfl_xor(amax, off));
    __shared__ float smax[4];
    if ((t & 63) == 0) smax[t >> 6] = amax;
    __syncthreads();
    amax = fmaxf(fmaxf(smax[0], smax[1]), fmaxf(smax[2], smax[3]));

    const float s = fmaxf(amax, EPSQ) / Q_MAX;   // clip(max|x|,EPS)/127 in fp32
    if (t == 0) scales[row] = s;

    int8_t q[16];
#pragma unroll
    for (int i = 0; i < 16; ++i) q[i] = (int8_t)__float2int_rn(vals[i] / s);  // rn = half-to-even

    *(int4*)(xq + (size_t)row * K + 16 * t) = *(const int4*)q;
}

// ---------------- int8 GEMM (ws paths): C[m,n]=sum_k A[m,k]*W[n,k] -------------------
template <bool PACKED_W>
__global__ __launch_bounds__(256) void gemm_i8(const int8_t* __restrict__ A,
                                               const int8_t* __restrict__ B8,
                                               const int* __restrict__ B32,
                                               const float* __restrict__ scales,   // [M]
                                               const float* __restrict__ scw,      // [N]
                                               const float* __restrict__ bias,     // [N] f32
                                               float* __restrict__ out,            // [M,N] f32
                                               int M, int N, int K) {
    __shared__ __align__(16) int8_t As[BM * BK];
    __shared__ __align__(16) int8_t Bs[BN * BK];

    const int t = threadIdx.x;
    const int w = t >> 6;
    const int l = t & 63;
    const int wm = w & 1;
    const int wn = w >> 1;
    const int bm = blockIdx.x * BM;
    const int bn = blockIdx.y * BN;

    // A staging (async16): physical slot row r = w*32+{0,16}+(l>>2), chunk c = l&3.
    // XOR swizzle: physical chunk c of row r holds logical k-chunk q = c ^ ((r>>1)&3).
    const int rA0 = w * 32 + (l >> 2);
    const int rA1 = rA0 + 16;
    const int cq0 = (l & 3) ^ ((rA0 >> 1) & 3);
    const int cq1 = (l & 3) ^ ((rA1 >> 1) & 3);
    const int8_t* gA0 = A + (size_t)(bm + rA0) * K + cq0 * 16;
    const int8_t* gA1 = A + (size_t)(bm + rA1) * K + cq1 * 16;
    int8_t* lA0 = As + w * 2048;            // wave-uniform base (HW adds lane*16)
    int8_t* lA1 = As + w * 2048 + 1024;

    // B staging mode 1 (packed int8, async16)
    const int8_t* gB0 = PACKED_W ? (B8 + (size_t)(bn + rA0) * K + cq0 * 16) : nullptr;
    const int8_t* gB1 = PACKED_W ? (B8 + (size_t)(bn + rA1) * K + cq1 * 16) : nullptr;
    int8_t* lB0 = Bs + w * 2048;
    int8_t* lB1 = Bs + w * 2048 + 1024;

    // B staging mode 2 (raw int32, register pack + ds_write); same swizzle
    const int rB   = t >> 1;
    const int half = t & 1;
    const int swB  = (rB >> 1) & 3;
    int8_t* dstB0 = Bs + rB * 64 + (((half * 2)     ^ swB) * 16);
    int8_t* dstB1 = Bs + rB * 64 + (((half * 2 + 1) ^ swB) * 16);
    const int* gB32 = PACKED_W ? nullptr : (B32 + (size_t)(bn + rB) * K + half * 32);

    // fragment reads: m/n = lane&15, logical k-chunk q = lane>>4
    const int fr = l & 15;
    const int fc = (l >> 4) ^ ((fr >> 1) & 3);
    const int aoff = (wm * 64 + fr) * 64 + fc * 16;
    const int boff = (wn * 64 + fr) * 64 + fc * 16;

    v4i acc[4][4] = {};

    for (int kt = 0; kt < K; kt += BK) {
        __syncthreads();
        async16(gA0 + kt, lA0);
        async16(gA1 + kt, lA1);
        if (PACKED_W) {
            async16(gB0 + kt, lB0);
            async16(gB1 + kt, lB1);
        } else {
            const int4* g4 = (const int4*)(gB32 + kt);
            int4 u0 = g4[0], u1 = g4[1], u2 = g4[2], u3 = g4[3];
            int4 u4 = g4[4], u5 = g4[5], u6 = g4[6], u7 = g4[7];
            int p0[4] = { pack4i(u0.x,u0.y,u0.z,u0.w), pack4i(u1.x,u1.y,u1.z,u1.w),
                          pack4i(u2.x,u2.y,u2.z,u2.w), pack4i(u3.x,u3.y,u3.z,u3.w) };
            int p1[4] = { pack4i(u4.x,u4.y,u4.z,u4.w), pack4i(u5.x,u5.y,u5.z,u5.w),
                          pack4i(u6.x,u6.y,u6.z,u6.w), pack4i(u7.x,u7.y,u7.z,u7.w) };
            *(int4*)dstB0 = *(const int4*)p0;
            *(int4*)dstB1 = *(const int4*)p1;
        }
        __syncthreads();

        v4i a[4], b[4];
#pragma unroll
        for (int i = 0; i < 4; ++i) a[i] = *(const v4i*)(As + aoff + i * 16 * 64);
#pragma unroll
        for (int j = 0; j < 4; ++j) b[j] = *(const v4i*)(Bs + boff + j * 16 * 64);
#pragma unroll
        for (int i = 0; i < 4; ++i)
#pragma unroll
            for (int j = 0; j < 4; ++j)
                acc[i][j] = __builtin_amdgcn_mfma_i32_16x16x64_i8(a[i], b[j], acc[i][j], 0, 0, 0);
    }

    // epilogue: C/D layout col=lane&15, row=(lane>>4)*4+reg
    const int colb = bn + wn * 64 + (l & 15);
#pragma unroll
    for (int i = 0; i < 4; ++i) {
        const int m0 = bm + wm * 64 + i * 16 + (l >> 4) * 4;
#pragma unroll
        for (int r = 0; r < 4; ++r) {
            const float sm = scales[m0 + r];
            float* orow = out + (size_t)(m0 + r) * N;
#pragma unroll
            for (int j = 0; j < 4; ++j) {
                const int n = colb + j * 16;
                orow[n] = ep((float)acc[i][j][r] * sm * scw[n], bias[n]);
            }
        }
    }
}

// ---------------- fully fused zero-workspace fallback --------------------------------
__global__ __launch_bounds__(256) void w8a8_fused(const float* __restrict__ x,
                                                  const int* __restrict__ w32,
                                                  const float* __restrict__ scw,
                                                  const float* __restrict__ bias,
                                                  float* __restrict__ out,
                                                  int M, int N, int K) {
    __shared__ __align__(16) int8_t As[BM * BK];
    __shared__ __align__(16) int8_t Bs[BN * BK];
    __shared__ float sS[BM];
    __shared__ float sR[BM];

    const int t = threadIdx.x;
    const int w = t >> 6;
    const int l = t & 63;
    const int wm = w & 1;
    const int wn = w >> 1;
    const int bm = blockIdx.x * BM;
    const int bn = blockIdx.y * BN;

    const int rloc = t >> 1;
    const int half = t & 1;

    {   // per-row absmax (2 threads/row, K/2 floats each)
        const float4* p = (const float4*)(x + (size_t)(bm + rloc) * K) + half * (K / 8);
        float amax = 0.f;
        for (int i = 0; i < K / 8; ++i) {
            float4 v = p[i];
            amax = fmaxf(amax, fmaxf(fmaxf(fabsf(v.x), fabsf(v.y)), fmaxf(fabsf(v.z), fabsf(v.w))));
        }
        amax = fmaxf(amax, __shfl_xor(amax, 1));
        if (half == 0) {
            const float s = fmaxf(amax, EPSQ) / Q_MAX;
            sS[rloc] = s;
            sR[rloc] = 1.0f / s;
        }
    }
    __syncthreads();
    const float rs = sR[rloc];

    const int swz = (rloc >> 1) & 3;
    int8_t* dA0 = As + rloc * 64 + (((half * 2)     ^ swz) * 16);
    int8_t* dA1 = As + rloc * 64 + (((half * 2 + 1) ^ swz) * 16);
    int8_t* dB0 = Bs + rloc * 64 + (((half * 2)     ^ swz) * 16);
    int8_t* dB1 = Bs + rloc * 64 + (((half * 2 + 1) ^ swz) * 16);
    const float* gA = x   + (size_t)(bm + rloc) * K + half * 32;
    const int*   gB = w32 + (size_t)(bn + rloc) * K + half * 32;

    const int fr = l & 15;
    const int fc = (l >> 4) ^ ((fr >> 1) & 3);
    const int aoff = (wm * 64 + fr) * 64 + fc * 16;
    const int boff = (wn * 64 + fr) * 64 + fc * 16;

    v4i acc[4][4] = {};

    for (int kt = 0; kt < K; kt += BK) {
        __syncthreads();
        {
            const float4* g4 = (const float4*)(gA + kt);
            float vv[32];
#pragma unroll
            for (int c = 0; c < 8; ++c) *(float4*)(vv + c * 4) = g4[c];
            int q[32];
#pragma unroll
            for (int j = 0; j < 32; ++j) q[j] = __float2int_rn(vv[j] * rs);
            int p0[4], p1[4];
#pragma unroll
            for (int c = 0; c < 4; ++c) {
                p0[c] = pack4i(q[c*4+0],    q[c*4+1],    q[c*4+2],    q[c*4+3]);
                p1[c] = pack4i(q[16+c*4+0], q[16+c*4+1], q[16+c*4+2], q[16+c*4+3]);
            }
            *(int4*)dA0 = *(const int4*)p0;
            *(int4*)dA1 = *(const int4*)p1;
        }
        {
            const int4* g4 = (const int4*)(gB + kt);
            int4 u0 = g4[0], u1 = g4[1], u2 = g4[2], u3 = g4[3];
            int4 u4 = g4[4], u5 = g4[5], u6 = g4[6], u7 = g4[7];
            int p0[4] = { pack4i(u0.x,u0.y,u0.z,u0.w), pack4i(u1.x,u1.y,u1.z,u1.w),
                          pack4i(u2.x,u2.y,u2.z,u2.w), pack4i(u3.x,u3.y,u3.z,u3.w) };
            int p1[4] = { pack4i(u4.x,u4.y,u4.z,u4.w), pack4i(u5.x,u5.y,u5.z,u5.w),
                          pack4i(u6.x,u6.y,u6.z,u6.w), pack4i(u7.x,u7.y,u7.z,u7.w) };
            *(int4*)dB0 = *(const int4*)p0;
            *(int4*)dB1 = *(const int4*)p1;
        }
        __syncthreads();

        v4i a[4], b[4];
#pragma unroll
        for (int i = 0; i < 4; ++i) a[i] = *(const v4i*)(As + aoff + i * 16 * 64);
#pragma unroll
        for (int j = 0; j < 4; ++j) b[j] = *(const v4i*)(Bs + boff + j * 16 * 64);
#pragma unroll
        for (int i = 0; i < 4; ++i)
#pragma unroll
            for (int j = 0; j < 4; ++j)
                acc[i][j] = __builtin_amdgcn_mfma_i32_16x16x64_i8(a[i], b[j], acc[i][j], 0, 0, 0);
    }

    const int colb = bn + wn * 64 + (l & 15);
#pragma unroll
    for (int i = 0; i < 4; ++i) {
        const int r0 = wm * 64 + i * 16 + (l >> 4) * 4;
#pragma unroll
        for (int r = 0; r < 4; ++r) {
            const float sm = sS[r0 + r];
            float* orow = out + (size_t)(bm + r0 + r) * N;
#pragma unroll
            for (int j = 0; j < 4; ++j) {
                const int n = colb + j * 16;
                orow[n] = ep((float)acc[i][j][r] * sm * scw[n], bias[n]);
            }
        }
    }
}

extern "C" void kernel_launch(void* const* d_in, const int* in_sizes, int n_in,
                              void* d_out, int out_size, void* d_ws, size_t ws_size,
                              hipStream_t stream) {
    const float* x    = (const float*)d_in[0];   // f32 (fp16 reference values)
    const int*   wgt  = (const int*)d_in[1];     // int32 (int8 values)
    const float* scw  = (const float*)d_in[2];
    const float* bias = (const float*)d_in[3];   // f32 (fp16 reference values)
    float* out = (float*)d_out;                  // f32 output

    const int N = in_sizes[2];                 // 11008
    const int K = in_sizes[1] / N;             // 4096
    const int M = in_sizes[0] / K;             // 4096

    float*  scales = (float*)d_ws;
    int8_t* xq     = (int8_t*)d_ws + (size_t)M * 4;
    const size_t need_mid  = (size_t)M * 4 + (size_t)M * K;
    const size_t need_fast = need_mid + (size_t)N * K;

    dim3 grid(M / BM, N / BN);
    if (ws_size >= need_fast) {
        quant_rows<<<M, 256, 0, stream>>>(x, xq, scales, K);
        int8_t* w8 = xq + (size_t)M * K;
        pack_w<<<(int)(((size_t)N * K) / (256 * 16)), 256, 0, stream>>>(wgt, w8);
        gemm_i8<true><<<grid, 256, 0, stream>>>(xq, w8, nullptr, scales, scw, bias, out, M, N, K);
    } else if (ws_size >= need_mid) {
        quant_rows<<<M, 256, 0, stream>>>(x, xq, scales, K);
        gemm_i8<false><<<grid, 256, 0, stream>>>(xq, nullptr, wgt, scales, scw, bias, out, M, N, K);
    } else {
        w8a8_fused<<<grid, 256, 0, stream>>>(x, wgt, scw, bias, out, M, N, K);
    }
}